// Round 10
// baseline (306.012 us; speedup 1.0000x reference)
//
#include <hip/hip_runtime.h>
#include <hip/hip_bf16.h>
#include <stdint.h>

// ---------------------------------------------------------------------------
// DiagonalElman on MI355X (gfx950)
//   W_comb = W_x @ W_in                  (small bf16 GEMM, frag-order out)
//   [xproj | xw] = x @ [W_in ; W_comb]^T (fused bf16 GEMM, bf16 out)
//   scan: h_t = tanh(xw_t + a*h_{t-1} + b); cell = h * silu(xproj + b_gate)
//   out    = cell @ W_out^T              (bf16 GEMM, fp32 out)
//
// R13: 4-wave GEMM, 128x128 output per wave. R9 post-mortem: per-CU-tile
// LDS-read wall (192KB ~ 2260cy) > MFMA wall (2067cy) — reads are inflated
// by operand duplication (A read by 4 waves, B by 2). 2Mx2N wave grid cuts
// per-CU-tile reads to 128KB (~1506cy) < MFMA wall. acc = 256 VGPR/lane ->
// 1 wave/SIMD (__launch_bounds__(256,1), 512-VGPR budget, est ~340 used);
// latency hiding is pure ILP (16 indep ds_reads + 64 indep-acc MFMAs per
// k-half). Schedule = R7 (one barrier/K-tile, stagger REVERTED — falsified).
// Staging: waves 0,1 stage A halves, waves 2,3 stage B halves; 16
// global_load_lds x 16B per thread per tile. Hazard ledger as R7:
// stage(t+1)->buf[(t+1)&1], last readers drained at t-1's lgkmcnt(0)+bar;
// per-wave vmcnt(0) before bar publishes staged tile.
// LDS layout per buffer: A 32KB then B 32KB; group G = rb_local*2 + kb at
// byte (G<<10); global src group = ((rnBase+rb)*KBg + 2t+kb)<<10 + lane*16.
// Fragment flat layout for [R x K] (16B units):
//   unit = (rb*KB + kb)*64 + lane,  rb=r>>4, kb=k>>5,
//   lane = (r&15) | (((k>>3)&3)<<4), elem j = k&7.
// ---------------------------------------------------------------------------

typedef __bf16 bf16x8 __attribute__((ext_vector_type(8)));
typedef float  f32x4  __attribute__((ext_vector_type(4)));

#define AS1 __attribute__((address_space(1)))
#define AS3 __attribute__((address_space(3)))

__device__ __forceinline__ unsigned short f2bf(float f) {
  uint32_t u = __float_as_uint(f);
  uint32_t r = (u + 0x7FFFu + ((u >> 16) & 1u)) >> 16;
  return (unsigned short)r;
}
__device__ __forceinline__ float bf2f(uint32_t h) {
  return __uint_as_float(h << 16);
}
__device__ __forceinline__ float tanh_fast(float x) {
  float e = __expf(2.0f * x);
  return 1.0f - 2.0f / (e + 1.0f);
}

// ---------------------------------------------------------------------------
// fp32 [R x K] row-major -> bf16 fragment order (bodies shared by kernels).
// ---------------------------------------------------------------------------
__device__ __forceinline__ void frag_rm_body(
    const float* __restrict__ W, unsigned short* __restrict__ out,
    int u, int K, int KB) {
  const int lane = u & 63;
  const int grp  = u >> 6;
  const int n = (grp / KB) * 16 + (lane & 15);
  const int k = (grp % KB) * 32 + ((lane >> 4) & 3) * 8;
  const float4* p = (const float4*)(W + (size_t)n * K + k);
  float4 a = p[0], b = p[1];
  union { unsigned short us[8]; uint4 v; } r;
  r.us[0] = f2bf(a.x); r.us[1] = f2bf(a.y); r.us[2] = f2bf(a.z); r.us[3] = f2bf(a.w);
  r.us[4] = f2bf(b.x); r.us[5] = f2bf(b.y); r.us[6] = f2bf(b.z); r.us[7] = f2bf(b.w);
  *(uint4*)(out + (size_t)u * 8) = r.v;
}

__device__ __forceinline__ void frag_tr_body(
    const float* __restrict__ W, unsigned short* __restrict__ out,
    int u, int N, int KB) {
  const int lane = u & 63;
  const int grp  = u >> 6;
  const int n = (grp / KB) * 16 + (lane & 15);
  const int k = (grp % KB) * 32 + ((lane >> 4) & 3) * 8;
  union { unsigned short us[8]; uint4 v; } r;
#pragma unroll
  for (int j = 0; j < 8; ++j) r.us[j] = f2bf(W[(size_t)(k + j) * N + n]);
  *(uint4*)(out + (size_t)u * 8) = r.v;
}

// one launch: blocks [0,xBlocks) swizzle x; then 4 weight jobs of wBlocks.
__global__ __launch_bounds__(256) void frag_all(
    const float* __restrict__ x,
    const float* __restrict__ Wx, const float* __restrict__ Win,
    const float* __restrict__ Wout,
    unsigned short* __restrict__ xfrag,
    unsigned short* __restrict__ WxF, unsigned short* __restrict__ WinTF,
    unsigned short* __restrict__ WcatF, unsigned short* __restrict__ WoutF,
    int Kd, int KB, int xBlocks, int wBlocks) {
  if (blockIdx.x < (unsigned)xBlocks) {
    const int u = blockIdx.x * 256 + threadIdx.x;
    frag_rm_body(x, xfrag, u, Kd, KB);
    return;
  }
  const int wb = blockIdx.x - xBlocks;
  const int job = wb / wBlocks;
  const int u = (wb - job * wBlocks) * 256 + threadIdx.x;
  if (job == 0)      frag_rm_body(Wx,  WxF,   u, Kd, KB);
  else if (job == 1) frag_tr_body(Win, WinTF, u, Kd, KB);
  else if (job == 2) frag_rm_body(Win, WcatF, u, Kd, KB);
  else               frag_rm_body(Wout, WoutF, u, Kd, KB);
}

// ---------------------------------------------------------------------------
// Small bf16 MFMA GEMM (128x128 tile, register-streaming, no LDS).
// SM: 0 = fp32 row-major C, 1 = bf16 row-major C, 2 = bf16 FRAGMENT-order C.
// ---------------------------------------------------------------------------
#define BM 128
#define BN 128

template <int SM>
__global__ __launch_bounds__(256) void gemm_frag(
    const unsigned short* __restrict__ Af, const unsigned short* __restrict__ Bf,
    void* __restrict__ Cv, int M, int N, int K) {
  const int tid  = threadIdx.x;
  const int lane = tid & 63;
  const int wave = tid >> 6;
  const int wrow = wave >> 1;
  const int wcol = wave & 1;
  const int rowBase = blockIdx.x * BM;
  const int colBase = blockIdx.y * BN;
  const int q   = lane >> 4;
  const int r16 = lane & 15;
  const int KB  = K >> 5;

  const unsigned short* ap[4];
  const unsigned short* bp[4];
#pragma unroll
  for (int i = 0; i < 4; ++i) {
    const int rb = (rowBase >> 4) + wrow * 4 + i;
    const int nb = (colBase >> 4) + wcol * 4 + i;
    ap[i] = Af + ((size_t)rb * KB * 64 + lane) * 8;
    bp[i] = Bf + ((size_t)nb * KB * 64 + lane) * 8;
  }

  f32x4 acc[4][4] = {};
  bf16x8 a0[4], b0[4];
#pragma unroll
  for (int i = 0; i < 4; ++i) {
    a0[i] = *(const bf16x8*)ap[i];
    b0[i] = *(const bf16x8*)bp[i];
  }

  for (int kb = 0; kb < KB; ++kb) {
    const size_t noff = (size_t)((kb + 1 < KB) ? kb + 1 : kb) * 512;
    bf16x8 a1[4], b1[4];
#pragma unroll
    for (int i = 0; i < 4; ++i) {
      a1[i] = *(const bf16x8*)(ap[i] + noff);
      b1[i] = *(const bf16x8*)(bp[i] + noff);
    }
#pragma unroll
    for (int i = 0; i < 4; ++i)
#pragma unroll
      for (int j = 0; j < 4; ++j)
        acc[i][j] = __builtin_amdgcn_mfma_f32_16x16x32_bf16(a0[i], b0[j], acc[i][j], 0, 0, 0);
#pragma unroll
    for (int i = 0; i < 4; ++i) { a0[i] = a1[i]; b0[i] = b1[i]; }
  }

  // epilogue: C/D layout col = lane&15, row = (lane>>4)*4 + reg
#pragma unroll
  for (int i = 0; i < 4; ++i) {
#pragma unroll
    for (int j = 0; j < 4; ++j) {
#pragma unroll
      for (int rg = 0; rg < 4; ++rg) {
        long long row = rowBase + wrow * 64 + i * 16 + q * 4 + rg;
        long long col = colBase + wcol * 64 + j * 16 + r16;
        float v = acc[i][j][rg];
        if (SM == 0) {
          ((float*)Cv)[row * (long long)N + col] = v;
        } else if (SM == 1) {
          ((unsigned short*)Cv)[row * (long long)N + col] = f2bf(v);
        } else {
          // fragment order: C treated as [M rows, N=K cols] operand
          const int KBo = N >> 5;
          long long unit = (((row >> 4) * (long long)KBo + (col >> 5)) << 6) +
                           ((row & 15) | ((((int)col >> 3) & 3) << 4));
          ((unsigned short*)Cv)[unit * 8 + (col & 7)] = f2bf(v);
        }
      }
    }
  }
}

// ---------------------------------------------------------------------------
// 256x256-tile bf16 MFMA GEMM, 4 waves (2Mx2N), 128x128 output per wave.
// C[m,n] = sum_k A[m,k]*B[n,k]. A,B fragment order. M,N%256==0, K%64==0,
// K/64>=2. 256 thr, 1 wave/SIMD (launch_bounds 256,1 -> 512-VGPR budget).
// blockIdx.x = M-tile, blockIdx.y = N-tile. ONE barrier per K-tile (R7).
// LDS 128 KiB = 2 dbuf x (A 32KB + B 32KB); group G=rb_local*2+kb at G<<10.
// Staging: wave 0 -> A rb 0-7, wave 1 -> A rb 8-15, wave 2 -> B nb 0-7,
// wave 3 -> B nb 8-15; 16 global_load_lds x 16B per thread per tile.
// ---------------------------------------------------------------------------
template <int SM>
__global__ __launch_bounds__(256, 1) void gemm256w4(
    const unsigned short* __restrict__ Af, const unsigned short* __restrict__ Bf,
    void* __restrict__ Cv, int N, int K) {
  __shared__ __attribute__((aligned(128))) char smem[131072];
  const int tid  = threadIdx.x;
  const int lane = tid & 63;
  const int w    = tid >> 6;   // 0..3
  const int wr   = w >> 1;     // 0..1  (M half)
  const int wc   = w & 1;      // 0..1  (N half)
  const int KBg  = K >> 5;     // global 32-k block count
  const int NT   = K >> 6;     // 64-k tiles
  const int rbBase = blockIdx.x << 4;   // M-tile
  const int nbBase = blockIdx.y << 4;   // N-tile

  // staging role: waves 0,1 -> A (halves 0,1); waves 2,3 -> B (halves 0,1)
  const char* gsb  = (w >> 1) ? (const char*)Bf : (const char*)Af;
  const int  rnB   = (w >> 1) ? nbBase : rbBase;
  const int  ldsOp = (w >> 1) ? 32768 : 0;
  const int  gof   = (w & 1) << 4;   // group offset 0 or 16

  f32x4 acc[8][8] = {};

#define STAGE(tt)                                                               \
  {                                                                             \
    _Pragma("unroll")                                                           \
    for (int i_ = 0; i_ < 16; ++i_) {                                           \
      const int G_ = gof + i_;                                                  \
      const size_t go_ = (((size_t)(rnB + (G_ >> 1)) * KBg +                    \
                           (size_t)(((tt) << 1) + (G_ & 1))) << 10) +           \
                         (size_t)(lane << 4);                                   \
      __builtin_amdgcn_global_load_lds((AS1 void*)(gsb + go_),                  \
          (AS3 void*)(smem + (((tt) & 1) << 16) + ldsOp + (G_ << 10)),          \
          16, 0, 0);                                                            \
    }                                                                           \
  }
#define BAR() asm volatile("s_barrier" ::: "memory")

  // prologue: stage tile0 (16 loads/thread); drain; publish.
  STAGE(0);
  asm volatile("s_waitcnt vmcnt(0)" ::: "memory");
  BAR();

  for (int t = 0; t < NT; ++t) {
    const char* LA = smem + ((t & 1) << 16);
    const char* LB = LA + 32768;
    bf16x8 a[8], b[8];

    // ---- k-half 0: reads, stage(t+1), MFMA 64
#pragma unroll
    for (int j = 0; j < 8; ++j)
      b[j] = *(const bf16x8*)(LB + ((((wc << 3) + j) << 1) << 10) + (lane << 4));
#pragma unroll
    for (int i = 0; i < 8; ++i)
      a[i] = *(const bf16x8*)(LA + ((((wr << 3) + i) << 1) << 10) + (lane << 4));
    if (t + 1 < NT) STAGE(t + 1);
    __builtin_amdgcn_s_setprio(1);
#pragma unroll
    for (int i = 0; i < 8; ++i)
#pragma unroll
      for (int j = 0; j < 8; ++j)
        acc[i][j] = __builtin_amdgcn_mfma_f32_16x16x32_bf16(a[i], b[j], acc[i][j], 0, 0, 0);
    __builtin_amdgcn_s_setprio(0);

    // ---- k-half 1: reads, MFMA 64 (barrier-free after k0 -> compiler interleaves)
#pragma unroll
    for (int j = 0; j < 8; ++j)
      b[j] = *(const bf16x8*)(LB + (((((wc << 3) + j) << 1) + 1) << 10) + (lane << 4));
#pragma unroll
    for (int i = 0; i < 8; ++i)
      a[i] = *(const bf16x8*)(LA + (((((wr << 3) + i) << 1) + 1) << 10) + (lane << 4));
    __builtin_amdgcn_s_setprio(1);
#pragma unroll
    for (int i = 0; i < 8; ++i)
#pragma unroll
      for (int j = 0; j < 8; ++j)
        acc[i][j] = __builtin_amdgcn_mfma_f32_16x16x32_bf16(a[i], b[j], acc[i][j], 0, 0, 0);
    __builtin_amdgcn_s_setprio(0);

    // tile boundary: own ds_reads drained (staging can't race them), own
    // staged loads landed; nothing may sink past here (rule #18 fence).
    asm volatile("s_waitcnt lgkmcnt(0)" ::: "memory");
    if (t + 1 < NT) asm volatile("s_waitcnt vmcnt(0)" ::: "memory");
    __builtin_amdgcn_sched_barrier(0);
    BAR();
  }
#undef STAGE
#undef BAR

  // epilogue: C/D layout col = lane&15, row = (lane>>4)*4 + reg
  const int q = lane >> 4, r16 = lane & 15;
#pragma unroll
  for (int i = 0; i < 8; ++i) {
#pragma unroll
    for (int j = 0; j < 8; ++j) {
#pragma unroll
      for (int rg = 0; rg < 4; ++rg) {
        long long row = (long long)blockIdx.x * 256 + wr * 128 + i * 16 + q * 4 + rg;
        long long col = (long long)blockIdx.y * 256 + wc * 128 + j * 16 + r16;
        float v = acc[i][j][rg];
        if (SM == 0) ((float*)Cv)[row * (long long)N + col] = v;
        else ((unsigned short*)Cv)[row * (long long)N + col] = f2bf(v);
      }
    }
  }
}

// ---------------------------------------------------------------------------
// Chunked diagonal scan, 8 channels/thread, 16B coalesced loads/stores.
// xcat: [B*T, 2D] row-major, cols 0..D-1 = xproj, D..2D-1 = xw.
// cell written in A-fragment order: 8 consecutive d = one 16B frag unit.
// ---------------------------------------------------------------------------
__global__ __launch_bounds__(256) void scan_kernel8(
    const unsigned short* __restrict__ xcat,
    const float* __restrict__ h0, const float* __restrict__ araw,
    const float* __restrict__ bvec, const float* __restrict__ bgate,
    unsigned short* __restrict__ cell, float* __restrict__ hfin,
    int Bv, int T, int D, int NC, int CH, int WARM) {
  const int idx = blockIdx.x * 256 + threadIdx.x;
  const int D8  = D >> 3;
  const int BD8 = Bv * D8;
  const int c = idx / BD8;
  if (c >= NC) return;
  const int ld = idx - c * BD8;
  const int b = ld / D8;
  const int d = (ld - b * D8) << 3;

  float av[8], bb[8], bg[8], h[8];
  *(float4*)&av[0] = *(const float4*)&araw[d];
  *(float4*)&av[4] = *(const float4*)&araw[d + 4];
  *(float4*)&bb[0] = *(const float4*)&bvec[d];
  *(float4*)&bb[4] = *(const float4*)&bvec[d + 4];
  *(float4*)&bg[0] = *(const float4*)&bgate[d];
  *(float4*)&bg[4] = *(const float4*)&bgate[d + 4];
#pragma unroll
  for (int j = 0; j < 8; ++j) av[j] = 1.0f / (1.0f + __expf(-av[j]));

  const int tb = c * CH;
  const int te = (tb + CH < T) ? (tb + CH) : T;
  int t0 = tb - WARM;
  if (t0 <= 0) {
    t0 = 0;
    *(float4*)&h[0] = *(const float4*)&h0[b * D + d];
    *(float4*)&h[4] = *(const float4*)&h0[b * D + d + 4];
  } else {
#pragma unroll
    for (int j = 0; j < 8; ++j) h[j] = 0.0f;
  }

  const int N2 = 2 * D;
  long long off = ((long long)b * T + t0) * N2 + D + d;   // xw
  for (int t = t0; t < tb; ++t) {                          // warm-up
    union { unsigned short u[8]; uint4 v; } wv;
    wv.v = *(const uint4*)&xcat[off];
#pragma unroll
    for (int j = 0; j < 8; ++j)
      h[j] = tanh_fast(__builtin_fmaf(av[j], h[j], bf2f(wv.u[j]) + bb[j]));
    off += N2;
  }
  long long offp = ((long long)b * T + tb) * N2 + d;       // xproj
  const int KBS = D * 16;                                  // shorts per 16-row blk
  const int dconst = ((d >> 5) << 9) + (((d >> 3) & 3) << 7);
  int m = b * T + tb;
  long long offc = (long long)(m >> 4) * KBS + ((m & 15) << 3) + dconst;
  for (int t = tb; t < te; ++t) {
    union { unsigned short u[8]; uint4 v; } wv, pv, ov;
    wv.v = *(const uint4*)&xcat[off];
    pv.v = *(const uint4*)&xcat[offp];
#pragma unroll
    for (int j = 0; j < 8; ++j) {
      h[j] = tanh_fast(__builtin_fmaf(av[j], h[j], bf2f(wv.u[j]) + bb[j]));
      float z = bf2f(pv.u[j]) + bg[j];
      float oo = h[j] * z / (1.0f + __expf(-z));
      ov.u[j] = f2bf(oo);
    }
    *(uint4*)&cell[offc] = ov.v;
    off += N2; offp += N2;
    ++m;
    offc += 8;
    if ((m & 15) == 0) offc += (long long)KBS - 128;
  }
  if (te == T) {
    *(float4*)&hfin[b * D + d]     = *(float4*)&h[0];
    *(float4*)&hfin[b * D + d + 4] = *(float4*)&h[4];
  }
}

// ---------------------------------------------------------------------------
extern "C" void kernel_launch(void* const* d_in, const int* in_sizes, int n_in,
                              void* d_out, int out_size, void* d_ws, size_t ws_size,
                              hipStream_t stream) {
  const float* x         = (const float*)d_in[0];
  const float* h0        = (const float*)d_in[1];
  const float* W_in      = (const float*)d_in[2];
  const float* W_x       = (const float*)d_in[3];
  const float* alpha_raw = (const float*)d_in[4];
  const float* b         = (const float*)d_in[5];
  const float* b_gate    = (const float*)d_in[6];
  const float* W_out     = (const float*)d_in[7];

  const int D  = in_sizes[4];
  const int BD = in_sizes[1];
  const int Bv = BD / D;
  const int M  = in_sizes[0] / D;   // B*T
  const int T  = M / Bv;
  const int KB = D >> 5;

  float* out  = (float*)d_out;                 // [M, D]
  float* hfin = out + (long long)M * D;        // [B, D]

  const size_t szXf  = (size_t)M * D * 2;      // bf16 frag [M,K=D]
  const size_t szCat = (size_t)M * D * 4;      // bf16 [M,2D] row-major
  const size_t szW   = (size_t)D * D * 2;      // bf16 [D,D]

  char* ws = (char*)d_ws;
  unsigned short* xfrag = (unsigned short*)ws; ws += szXf;
  unsigned short* xcat  = (unsigned short*)ws; ws += szCat;
  unsigned short* WcatF = (unsigned short*)ws; ws += 2 * szW;  // frag [2D, K=D]
  unsigned short* WoutF = (unsigned short*)ws; ws += szW;      // frag [D, K=D]
  // temporaries aliased inside xcat (dead before fused GEMM writes xcat):
  unsigned short* WxF    = xcat;
  unsigned short* WinTF  = xcat + (size_t)D * D;
  unsigned short* cell   = xfrag;              // xfrag dead after fused GEMM
  unsigned short* WcombF = WcatF + (size_t)D * D;

  const int xBlocks = (int)((size_t)M * D / 2048);
  const int wBlocks = (int)((size_t)D * D / 2048);

  frag_all<<<xBlocks + 4 * wBlocks, 256, 0, stream>>>(
      x, W_x, W_in, W_out, xfrag, WxF, WinTF, WcatF, WoutF,
      D, KB, xBlocks, wBlocks);

  // W_comb = W_x @ W_in, written DIRECTLY in fragment order into WcatF 2nd half
  gemm_frag<2><<<dim3(D / BM, D / BN), 256, 0, stream>>>(WxF, WinTF, WcombF, D, D, D);

  // [xproj | xw] = x @ Wcat^T : M x 2D (row-major bf16 out)
  gemm256w4<1><<<dim3(M / 256, (2 * D) / 256), 256, 0, stream>>>(xfrag, WcatF, xcat, 2 * D, D);

  const int CH = 16;
  const int WARM = 8;
  const int NC = (T + CH - 1) / CH;
  const int total8 = NC * Bv * (D >> 3);
  scan_kernel8<<<(total8 + 255) / 256, 256, 0, stream>>>(
      xcat, h0, alpha_raw, b, b_gate, cell, hfin, Bv, T, D, NC, CH, WARM);

  // out = cell @ W_out^T (fp32 out)
  gemm256w4<0><<<dim3(M / 256, D / 256), 256, 0, stream>>>(cell, WoutF, out, D, D);
}

// Round 11
// 293.163 us; speedup vs baseline: 1.0438x; 1.0438x over previous
//
#include <hip/hip_runtime.h>
#include <hip/hip_bf16.h>
#include <stdint.h>

// ---------------------------------------------------------------------------
// DiagonalElman on MI355X (gfx950) — FINAL (R7 configuration, session-best)
//   W_comb = W_x @ W_in                  (small bf16 GEMM, frag-order out)
//   [xproj | xw] = x @ [W_in ; W_comb]^T (fused bf16 GEMM, bf16 out)
//   scan: h_t = tanh(xw_t + a*h_{t-1} + b); cell = h * silu(xproj + b_gate)
//   out    = cell @ W_out^T              (bf16 GEMM, fp32 out)
//
// GEMM: 256x256 tile, 8 waves (2Mx4N, 128x64/wave), BK=64 in 2 K-halves,
// 2 LDS double-buffers (128 KiB), ONE barrier per K-tile:
//   { reads k0 | stage(t+1) | MFMA k0 | reads k1 | MFMA k1 |
//     lgkmcnt(0) | vmcnt(0) | sched_barrier(0) | s_barrier }
// k1-reads sit barrier-free next to MFMA-k0 -> compiler's fine-grained
// lgkmcnt scheduling overlaps LDS and MFMA pipes within the wave.
// Experiment ledger (all within-session, counters in journal):
//   R4  N-tile-major grid     -> FETCH 49->135MB (A-reuse lost)   REVERTED
//   R8  B direct from L2      -> +900cy/tile exposed latency      REVERTED
//   R9  wave-phase stagger    -> split LDS streams, -13%          REVERTED
//   R10 4-wave 128x128/wave   -> 1 wave/SIMD, no TLP, -15%        REVERTED
// Register arithmetic: 104 VGPR + 128 AGPR/wave -> 2 waves/SIMD ->
// 1 block/CU at this tile shape; per-tile time = serial{MFMA 2483cy,
// LDS-read ~2260cy, stage ~500cy} ~= 5452cy measured. Structure-bound.
// Hazards: stage(t+1)->buf[(t+1)&1]; its last readers drained at t-1's
// lgkmcnt(0)+barrier; vmcnt(0)+barrier publishes staged tile; barrier
// counts wave-uniform; counted waits always retire (no deadlock).
// Fragment flat layout for [R x K] (16B units):
//   unit = (rb*KB + kb)*64 + lane,  rb=r>>4, kb=k>>5,
//   lane = (r&15) | (((k>>3)&3)<<4), elem j = k&7.
// ---------------------------------------------------------------------------

typedef __bf16 bf16x8 __attribute__((ext_vector_type(8)));
typedef float  f32x4  __attribute__((ext_vector_type(4)));

#define AS1 __attribute__((address_space(1)))
#define AS3 __attribute__((address_space(3)))

__device__ __forceinline__ unsigned short f2bf(float f) {
  uint32_t u = __float_as_uint(f);
  uint32_t r = (u + 0x7FFFu + ((u >> 16) & 1u)) >> 16;
  return (unsigned short)r;
}
__device__ __forceinline__ float bf2f(uint32_t h) {
  return __uint_as_float(h << 16);
}
__device__ __forceinline__ float tanh_fast(float x) {
  float e = __expf(2.0f * x);
  return 1.0f - 2.0f / (e + 1.0f);
}

// ---------------------------------------------------------------------------
// fp32 [R x K] row-major -> bf16 fragment order (bodies shared by kernels).
// ---------------------------------------------------------------------------
__device__ __forceinline__ void frag_rm_body(
    const float* __restrict__ W, unsigned short* __restrict__ out,
    int u, int K, int KB) {
  const int lane = u & 63;
  const int grp  = u >> 6;
  const int n = (grp / KB) * 16 + (lane & 15);
  const int k = (grp % KB) * 32 + ((lane >> 4) & 3) * 8;
  const float4* p = (const float4*)(W + (size_t)n * K + k);
  float4 a = p[0], b = p[1];
  union { unsigned short us[8]; uint4 v; } r;
  r.us[0] = f2bf(a.x); r.us[1] = f2bf(a.y); r.us[2] = f2bf(a.z); r.us[3] = f2bf(a.w);
  r.us[4] = f2bf(b.x); r.us[5] = f2bf(b.y); r.us[6] = f2bf(b.z); r.us[7] = f2bf(b.w);
  *(uint4*)(out + (size_t)u * 8) = r.v;
}

__device__ __forceinline__ void frag_tr_body(
    const float* __restrict__ W, unsigned short* __restrict__ out,
    int u, int N, int KB) {
  const int lane = u & 63;
  const int grp  = u >> 6;
  const int n = (grp / KB) * 16 + (lane & 15);
  const int k = (grp % KB) * 32 + ((lane >> 4) & 3) * 8;
  union { unsigned short us[8]; uint4 v; } r;
#pragma unroll
  for (int j = 0; j < 8; ++j) r.us[j] = f2bf(W[(size_t)(k + j) * N + n]);
  *(uint4*)(out + (size_t)u * 8) = r.v;
}

// one launch: blocks [0,xBlocks) swizzle x; then 4 weight jobs of wBlocks.
__global__ __launch_bounds__(256) void frag_all(
    const float* __restrict__ x,
    const float* __restrict__ Wx, const float* __restrict__ Win,
    const float* __restrict__ Wout,
    unsigned short* __restrict__ xfrag,
    unsigned short* __restrict__ WxF, unsigned short* __restrict__ WinTF,
    unsigned short* __restrict__ WcatF, unsigned short* __restrict__ WoutF,
    int Kd, int KB, int xBlocks, int wBlocks) {
  if (blockIdx.x < (unsigned)xBlocks) {
    const int u = blockIdx.x * 256 + threadIdx.x;
    frag_rm_body(x, xfrag, u, Kd, KB);
    return;
  }
  const int wb = blockIdx.x - xBlocks;
  const int job = wb / wBlocks;
  const int u = (wb - job * wBlocks) * 256 + threadIdx.x;
  if (job == 0)      frag_rm_body(Wx,  WxF,   u, Kd, KB);
  else if (job == 1) frag_tr_body(Win, WinTF, u, Kd, KB);
  else if (job == 2) frag_rm_body(Win, WcatF, u, Kd, KB);
  else               frag_rm_body(Wout, WoutF, u, Kd, KB);
}

// ---------------------------------------------------------------------------
// Small bf16 MFMA GEMM (128x128 tile, register-streaming, no LDS).
// SM: 0 = fp32 row-major C, 1 = bf16 row-major C, 2 = bf16 FRAGMENT-order C.
// ---------------------------------------------------------------------------
#define BM 128
#define BN 128

template <int SM>
__global__ __launch_bounds__(256) void gemm_frag(
    const unsigned short* __restrict__ Af, const unsigned short* __restrict__ Bf,
    void* __restrict__ Cv, int M, int N, int K) {
  const int tid  = threadIdx.x;
  const int lane = tid & 63;
  const int wave = tid >> 6;
  const int wrow = wave >> 1;
  const int wcol = wave & 1;
  const int rowBase = blockIdx.x * BM;
  const int colBase = blockIdx.y * BN;
  const int q   = lane >> 4;
  const int r16 = lane & 15;
  const int KB  = K >> 5;

  const unsigned short* ap[4];
  const unsigned short* bp[4];
#pragma unroll
  for (int i = 0; i < 4; ++i) {
    const int rb = (rowBase >> 4) + wrow * 4 + i;
    const int nb = (colBase >> 4) + wcol * 4 + i;
    ap[i] = Af + ((size_t)rb * KB * 64 + lane) * 8;
    bp[i] = Bf + ((size_t)nb * KB * 64 + lane) * 8;
  }

  f32x4 acc[4][4] = {};
  bf16x8 a0[4], b0[4];
#pragma unroll
  for (int i = 0; i < 4; ++i) {
    a0[i] = *(const bf16x8*)ap[i];
    b0[i] = *(const bf16x8*)bp[i];
  }

  for (int kb = 0; kb < KB; ++kb) {
    const size_t noff = (size_t)((kb + 1 < KB) ? kb + 1 : kb) * 512;
    bf16x8 a1[4], b1[4];
#pragma unroll
    for (int i = 0; i < 4; ++i) {
      a1[i] = *(const bf16x8*)(ap[i] + noff);
      b1[i] = *(const bf16x8*)(bp[i] + noff);
    }
#pragma unroll
    for (int i = 0; i < 4; ++i)
#pragma unroll
      for (int j = 0; j < 4; ++j)
        acc[i][j] = __builtin_amdgcn_mfma_f32_16x16x32_bf16(a0[i], b0[j], acc[i][j], 0, 0, 0);
#pragma unroll
    for (int i = 0; i < 4; ++i) { a0[i] = a1[i]; b0[i] = b1[i]; }
  }

  // epilogue: C/D layout col = lane&15, row = (lane>>4)*4 + reg
#pragma unroll
  for (int i = 0; i < 4; ++i) {
#pragma unroll
    for (int j = 0; j < 4; ++j) {
#pragma unroll
      for (int rg = 0; rg < 4; ++rg) {
        long long row = rowBase + wrow * 64 + i * 16 + q * 4 + rg;
        long long col = colBase + wcol * 64 + j * 16 + r16;
        float v = acc[i][j][rg];
        if (SM == 0) {
          ((float*)Cv)[row * (long long)N + col] = v;
        } else if (SM == 1) {
          ((unsigned short*)Cv)[row * (long long)N + col] = f2bf(v);
        } else {
          // fragment order: C treated as [M rows, N=K cols] operand
          const int KBo = N >> 5;
          long long unit = (((row >> 4) * (long long)KBo + (col >> 5)) << 6) +
                           ((row & 15) | ((((int)col >> 3) & 3) << 4));
          ((unsigned short*)Cv)[unit * 8 + (col & 7)] = f2bf(v);
        }
      }
    }
  }
}

// ---------------------------------------------------------------------------
// 256x256-tile bf16 MFMA GEMM, ONE barrier per K-tile (ILP pipe overlap).
// C[m,n] = sum_k A[m,k]*B[n,k]. A,B fragment order. M,N%256==0, K%64==0,
// K/64>=2. 512 thr = 8 waves (2M x 4N), wave owns 128x64 output.
// blockIdx.x = M-tile, blockIdx.y = N-tile.
// LDS 128 KiB = 2 dbuf x (A 32KB + B 32KB), tile split into 2 K-halves.
// ---------------------------------------------------------------------------
template <int SM>
__global__ __launch_bounds__(512, 2) void gemm256p(
    const unsigned short* __restrict__ Af, const unsigned short* __restrict__ Bf,
    void* __restrict__ Cv, int N, int K) {
  __shared__ __attribute__((aligned(128))) char smem[131072];
  const int tid  = threadIdx.x;
  const int lane = tid & 63;
  const int w    = tid >> 6;   // 0..7
  const int wr   = w >> 2;     // 0..1  (M half)
  const int wc   = w & 3;      // 0..3  (N quarter)
  const int KBg  = K >> 5;     // global 32-k block count
  const int NT   = K >> 6;     // 64-k tiles
  const int rbBase = blockIdx.x << 4;   // M-tile
  const int nbBase = blockIdx.y << 4;   // N-tile

  const char* Ab = (const char*)Af;
  const char* Bb = (const char*)Bf;

  f32x4 acc[8][4] = {};

#define STAGE_A(tt, hh)                                                         \
  {                                                                             \
    const int sb_ = (((tt) & 1) << 16) + ((hh) << 14);                          \
    _Pragma("unroll")                                                           \
    for (int i_ = 0; i_ < 2; ++i_) {                                            \
      const int g_ = (w << 1) + i_;                                             \
      const size_t go_ = (((size_t)(rbBase + g_) * KBg +                        \
                           (size_t)(((tt) << 1) + (hh))) << 10) +               \
                         (size_t)(lane << 4);                                   \
      __builtin_amdgcn_global_load_lds((AS1 void*)(Ab + go_),                   \
          (AS3 void*)(smem + sb_ + (g_ << 10)), 16, 0, 0);                      \
    }                                                                           \
  }
#define STAGE_B(tt, hh)                                                         \
  {                                                                             \
    const int sb_ = (((tt) & 1) << 16) + 32768 + ((hh) << 14);                  \
    _Pragma("unroll")                                                           \
    for (int i_ = 0; i_ < 2; ++i_) {                                            \
      const int g_ = (w << 1) + i_;                                             \
      const size_t go_ = (((size_t)(nbBase + g_) * KBg +                        \
                           (size_t)(((tt) << 1) + (hh))) << 10) +               \
                         (size_t)(lane << 4);                                   \
      __builtin_amdgcn_global_load_lds((AS1 void*)(Bb + go_),                   \
          (AS3 void*)(smem + sb_ + (g_ << 10)), 16, 0, 0);                      \
    }                                                                           \
  }
#define BAR() asm volatile("s_barrier" ::: "memory")

  // prologue: stage tile0 (8 loads); drain; publish.
  STAGE_A(0, 0); STAGE_B(0, 0);
  STAGE_A(0, 1); STAGE_B(0, 1);
  asm volatile("s_waitcnt vmcnt(0)" ::: "memory");
  BAR();

  for (int t = 0; t < NT; ++t) {
    const char* LA = smem + ((t & 1) << 16);
    const char* LB = LA + 32768;
    bf16x8 aL[4], aH[4], b0[4], b1[4];

    // reads k0
#pragma unroll
    for (int j = 0; j < 4; ++j)
      b0[j] = *(const bf16x8*)(LB + (((wc << 2) + j) << 10) + (lane << 4));
#pragma unroll
    for (int i = 0; i < 4; ++i)
      aL[i] = *(const bf16x8*)(LA + (((wr << 3) + i) << 10) + (lane << 4));
#pragma unroll
    for (int i = 0; i < 4; ++i)
      aH[i] = *(const bf16x8*)(LA + (((wr << 3) + 4 + i) << 10) + (lane << 4));
    // stage tile t+1 into the other buffer (its readers drained at t-1's bar)
    if (t + 1 < NT) {
      STAGE_A(t + 1, 0); STAGE_B(t + 1, 0);
      STAGE_A(t + 1, 1); STAGE_B(t + 1, 1);
    }
    // MFMA k0 (reads k1 below are barrier-free -> compiler interleaves)
    __builtin_amdgcn_s_setprio(1);
#pragma unroll
    for (int i = 0; i < 4; ++i)
#pragma unroll
      for (int j = 0; j < 4; ++j)
        acc[i][j] = __builtin_amdgcn_mfma_f32_16x16x32_bf16(aL[i], b0[j], acc[i][j], 0, 0, 0);
#pragma unroll
    for (int i = 0; i < 4; ++i)
#pragma unroll
      for (int j = 0; j < 4; ++j)
        acc[4 + i][j] = __builtin_amdgcn_mfma_f32_16x16x32_bf16(aH[i], b0[j], acc[4 + i][j], 0, 0, 0);
    __builtin_amdgcn_s_setprio(0);

    // reads k1
#pragma unroll
    for (int j = 0; j < 4; ++j)
      b1[j] = *(const bf16x8*)(LB + 16384 + (((wc << 2) + j) << 10) + (lane << 4));
#pragma unroll
    for (int i = 0; i < 4; ++i)
      aL[i] = *(const bf16x8*)(LA + 16384 + (((wr << 3) + i) << 10) + (lane << 4));
#pragma unroll
    for (int i = 0; i < 4; ++i)
      aH[i] = *(const bf16x8*)(LA + 16384 + (((wr << 3) + 4 + i) << 10) + (lane << 4));
    __builtin_amdgcn_s_setprio(1);
#pragma unroll
    for (int i = 0; i < 4; ++i)
#pragma unroll
      for (int j = 0; j < 4; ++j)
        acc[i][j] = __builtin_amdgcn_mfma_f32_16x16x32_bf16(aL[i], b1[j], acc[i][j], 0, 0, 0);
#pragma unroll
    for (int i = 0; i < 4; ++i)
#pragma unroll
      for (int j = 0; j < 4; ++j)
        acc[4 + i][j] = __builtin_amdgcn_mfma_f32_16x16x32_bf16(aH[i], b1[j], acc[4 + i][j], 0, 0, 0);
    __builtin_amdgcn_s_setprio(0);

    // tile boundary: own ds_reads drained (so staging can't race them),
    // staged loads landed, nothing may sink past here (rule #18 fence).
    asm volatile("s_waitcnt lgkmcnt(0)" ::: "memory");
    if (t + 1 < NT) asm volatile("s_waitcnt vmcnt(0)" ::: "memory");
    __builtin_amdgcn_sched_barrier(0);
    BAR();
  }
#undef STAGE_A
#undef STAGE_B
#undef BAR

  // epilogue: C/D layout col = lane&15, row = (lane>>4)*4 + reg
  const int q = lane >> 4, r16 = lane & 15;
#pragma unroll
  for (int i = 0; i < 8; ++i) {
#pragma unroll
    for (int j = 0; j < 4; ++j) {
#pragma unroll
      for (int rg = 0; rg < 4; ++rg) {
        long long row = (long long)blockIdx.x * 256 + wr * 128 + i * 16 + q * 4 + rg;
        long long col = (long long)blockIdx.y * 256 + wc * 64 + j * 16 + r16;
        float v = acc[i][j][rg];
        if (SM == 0) ((float*)Cv)[row * (long long)N + col] = v;
        else ((unsigned short*)Cv)[row * (long long)N + col] = f2bf(v);
      }
    }
  }
}

// ---------------------------------------------------------------------------
// Chunked diagonal scan, 8 channels/thread, 16B coalesced loads/stores.
// xcat: [B*T, 2D] row-major, cols 0..D-1 = xproj, D..2D-1 = xw.
// cell written in A-fragment order: 8 consecutive d = one 16B frag unit.
// ---------------------------------------------------------------------------
__global__ __launch_bounds__(256) void scan_kernel8(
    const unsigned short* __restrict__ xcat,
    const float* __restrict__ h0, const float* __restrict__ araw,
    const float* __restrict__ bvec, const float* __restrict__ bgate,
    unsigned short* __restrict__ cell, float* __restrict__ hfin,
    int Bv, int T, int D, int NC, int CH, int WARM) {
  const int idx = blockIdx.x * 256 + threadIdx.x;
  const int D8  = D >> 3;
  const int BD8 = Bv * D8;
  const int c = idx / BD8;
  if (c >= NC) return;
  const int ld = idx - c * BD8;
  const int b = ld / D8;
  const int d = (ld - b * D8) << 3;

  float av[8], bb[8], bg[8], h[8];
  *(float4*)&av[0] = *(const float4*)&araw[d];
  *(float4*)&av[4] = *(const float4*)&araw[d + 4];
  *(float4*)&bb[0] = *(const float4*)&bvec[d];
  *(float4*)&bb[4] = *(const float4*)&bvec[d + 4];
  *(float4*)&bg[0] = *(const float4*)&bgate[d];
  *(float4*)&bg[4] = *(const float4*)&bgate[d + 4];
#pragma unroll
  for (int j = 0; j < 8; ++j) av[j] = 1.0f / (1.0f + __expf(-av[j]));

  const int tb = c * CH;
  const int te = (tb + CH < T) ? (tb + CH) : T;
  int t0 = tb - WARM;
  if (t0 <= 0) {
    t0 = 0;
    *(float4*)&h[0] = *(const float4*)&h0[b * D + d];
    *(float4*)&h[4] = *(const float4*)&h0[b * D + d + 4];
  } else {
#pragma unroll
    for (int j = 0; j < 8; ++j) h[j] = 0.0f;
  }

  const int N2 = 2 * D;
  long long off = ((long long)b * T + t0) * N2 + D + d;   // xw
  for (int t = t0; t < tb; ++t) {                          // warm-up
    union { unsigned short u[8]; uint4 v; } wv;
    wv.v = *(const uint4*)&xcat[off];
#pragma unroll
    for (int j = 0; j < 8; ++j)
      h[j] = tanh_fast(__builtin_fmaf(av[j], h[j], bf2f(wv.u[j]) + bb[j]));
    off += N2;
  }
  long long offp = ((long long)b * T + tb) * N2 + d;       // xproj
  const int KBS = D * 16;                                  // shorts per 16-row blk
  const int dconst = ((d >> 5) << 9) + (((d >> 3) & 3) << 7);
  int m = b * T + tb;
  long long offc = (long long)(m >> 4) * KBS + ((m & 15) << 3) + dconst;
  for (int t = tb; t < te; ++t) {
    union { unsigned short u[8]; uint4 v; } wv, pv, ov;
    wv.v = *(const uint4*)&xcat[off];
    pv.v = *(const uint4*)&xcat[offp];
#pragma unroll
    for (int j = 0; j < 8; ++j) {
      h[j] = tanh_fast(__builtin_fmaf(av[j], h[j], bf2f(wv.u[j]) + bb[j]));
      float z = bf2f(pv.u[j]) + bg[j];
      float oo = h[j] * z / (1.0f + __expf(-z));
      ov.u[j] = f2bf(oo);
    }
    *(uint4*)&cell[offc] = ov.v;
    off += N2; offp += N2;
    ++m;
    offc += 8;
    if ((m & 15) == 0) offc += (long long)KBS - 128;
  }
  if (te == T) {
    *(float4*)&hfin[b * D + d]     = *(float4*)&h[0];
    *(float4*)&hfin[b * D + d + 4] = *(float4*)&h[4];
  }
}

// ---------------------------------------------------------------------------
extern "C" void kernel_launch(void* const* d_in, const int* in_sizes, int n_in,
                              void* d_out, int out_size, void* d_ws, size_t ws_size,
                              hipStream_t stream) {
  const float* x         = (const float*)d_in[0];
  const float* h0        = (const float*)d_in[1];
  const float* W_in      = (const float*)d_in[2];
  const float* W_x       = (const float*)d_in[3];
  const float* alpha_raw = (const float*)d_in[4];
  const float* b         = (const float*)d_in[5];
  const float* b_gate    = (const float*)d_in[6];
  const float* W_out     = (const float*)d_in[7];

  const int D  = in_sizes[4];
  const int BD = in_sizes[1];
  const int Bv = BD / D;
  const int M  = in_sizes[0] / D;   // B*T
  const int T  = M / Bv;
  const int KB = D >> 5;

  float* out  = (float*)d_out;                 // [M, D]
  float* hfin = out + (long long)M * D;        // [B, D]

  const size_t szXf  = (size_t)M * D * 2;      // bf16 frag [M,K=D]
  const size_t szCat = (size_t)M * D * 4;      // bf16 [M,2D] row-major
  const size_t szW   = (size_t)D * D * 2;      // bf16 [D,D]

  char* ws = (char*)d_ws;
  unsigned short* xfrag = (unsigned short*)ws; ws += szXf;
  unsigned short* xcat  = (unsigned short*)ws; ws += szCat;
  unsigned short* WcatF = (unsigned short*)ws; ws += 2 * szW;  // frag [2D, K=D]
  unsigned short* WoutF = (unsigned short*)ws; ws += szW;      // frag [D, K=D]
  // temporaries aliased inside xcat (dead before fused GEMM writes xcat):
  unsigned short* WxF    = xcat;
  unsigned short* WinTF  = xcat + (size_t)D * D;
  unsigned short* cell   = xfrag;              // xfrag dead after fused GEMM
  unsigned short* WcombF = WcatF + (size_t)D * D;

  const int xBlocks = (int)((size_t)M * D / 2048);
  const int wBlocks = (int)((size_t)D * D / 2048);

  frag_all<<<xBlocks + 4 * wBlocks, 256, 0, stream>>>(
      x, W_x, W_in, W_out, xfrag, WxF, WinTF, WcatF, WoutF,
      D, KB, xBlocks, wBlocks);

  // W_comb = W_x @ W_in, written DIRECTLY in fragment order into WcatF 2nd half
  gemm_frag<2><<<dim3(D / BM, D / BN), 256, 0, stream>>>(WxF, WinTF, WcombF, D, D, D);

  // [xproj | xw] = x @ Wcat^T : M x 2D (row-major bf16 out)
  gemm256p<1><<<dim3(M / 256, (2 * D) / 256), 512, 0, stream>>>(xfrag, WcatF, xcat, 2 * D, D);

  const int CH = 16;
  const int WARM = 8;
  const int NC = (T + CH - 1) / CH;
  const int total8 = NC * Bv * (D >> 3);
  scan_kernel8<<<(total8 + 255) / 256, 256, 0, stream>>>(
      xcat, h0, alpha_raw, b, b_gate, cell, hfin, Bv, T, D, NC, CH, WARM);

  // out = cell @ W_out^T (fp32 out)
  gemm256p<0><<<dim3(M / 256, D / 256), 512, 0, stream>>>(cell, WoutF, out, D, D);
}